// Round 10
// baseline (167.567 us; speedup 1.0000x reference)
//
#include <hip/hip_runtime.h>
#include <stdint.h>

typedef __attribute__((ext_vector_type(8))) short short8;
typedef __attribute__((ext_vector_type(4))) float floatx4;

#define B_   8
#define H_   16
#define N_   1024
#define D_   64
#define NH_  (B_*H_)
#define LOG2E 1.44269504088896340736f
#define IMG_SHORTS 4096          // 64*64 shorts = 8192 B per (head,chunk) image
#define NCHUNK 16

extern "C" {
__device__ float __ocml_native_exp2_f32(float);
__device__ float __ocml_native_rsqrt_f32(float);
}

// pack two f32 -> bf16x2 (round-half-up on magnitude; fine for our ranges)
__device__ __forceinline__ unsigned int pk2(float a, float b) {
    unsigned int ua = __float_as_uint(a) + 0x8000u;
    unsigned int ub = __float_as_uint(b) + 0x8000u;
    return __builtin_amdgcn_perm(ub, ua, 0x07060302);  // (bf(b)<<16)|bf(a)
}

// ---------------------------------------------------------------------------
// R10: 64 queries/wave (4 m-tiles). R9 budget: LDS-read ~20.5 us/CU (41%) and
// VALU ~20 us are the co-dominant pipes; frag reads (K/V operands) are shared
// across m-tiles, so doubling queries/wave halves per-CU LDS traffic at zero
// extra VALU/TRANS/MFMA total. Grid 256 blocks (1 block/CU, 2 waves/SIMD) --
// TLP was shown unproductive (R1 vs R3: 2x occupancy -> -7%), betting on
// within-wave ILP (4 independent t-streams) + halved LDS contention instead.
// launch_bounds(512,2) -> 256-VGPR cap (audit ~170). ONE compute body, static
// indexing only (anti-spill discipline: R4/R6/R8 all spilled via duplicated
// bodies/state; R7/R9 shape compiles lean). Counted-vmcnt pipeline kept
// (R9: 52.1 -> 50.1 us). setprio: permanently removed (~60% regression).
// Spill gate: WRITE_SIZE must stay ~33 MB.
// ---------------------------------------------------------------------------

// ============================ kernel 1: prep ================================
// grid = 128 heads * 16 chunks, 512 threads. Thread mapping identical to
// R5's stage(): w=tid>>6 (wave), lane=tid&63.
__global__ __launch_bounds__(512) void prep_kv(
    const float* __restrict__ k, const float* __restrict__ v,
    unsigned short* __restrict__ kimg, unsigned short* __restrict__ vimg)
{
    const int bid = blockIdx.x;
    const int head = bid >> 4, ck = bid & 15;
    const int tid = threadIdx.x, w = tid >> 6, lane = tid & 63;

    const float* kh = k + (size_t)head * N_ * D_;
    const float* vh = v + (size_t)head * N_ * D_;
    unsigned short* kd = kimg + ((size_t)(head * 16 + ck)) * IMG_SHORTS;
    unsigned short* vd = vimg + ((size_t)(head * 16 + ck)) * IMG_SHORTS;

    // K: thread owns key-row srow, 8 dims at d-block cbk = lane&7
    const int srow = w * 8 + (lane >> 3);
    const int cbk  = lane & 7;
    const int ksw  = srow & 7;
    const float* kp = kh + ((size_t)(ck * 64 + srow)) * D_ + cbk * 8;
    float4 kx0 = *(const float4*)(kp);
    float4 kx1 = *(const float4*)(kp + 4);
    float ss = kx0.x*kx0.x + kx0.y*kx0.y + kx0.z*kx0.z + kx0.w*kx0.w
             + kx1.x*kx1.x + kx1.y*kx1.y + kx1.z*kx1.z + kx1.w*kx1.w;
    ss += __shfl_xor(ss, 1);       // 8 lanes of same key cover dims 0..63
    ss += __shfl_xor(ss, 2);
    ss += __shfl_xor(ss, 4);
    float sc = __ocml_native_rsqrt_f32(ss);
    union { unsigned int u[4]; short8 s8; } pk;
    pk.u[0] = pk2(kx0.x*sc, kx0.y*sc); pk.u[1] = pk2(kx0.z*sc, kx0.w*sc);
    pk.u[2] = pk2(kx1.x*sc, kx1.y*sc); pk.u[3] = pk2(kx1.z*sc, kx1.w*sc);
    *(short8*)&kd[srow * 64 + ((cbk ^ ksw) << 3)] = pk.s8;               // b128

    // V^T: thread owns d = lane, phys key-block cb = w (8 logical keys)
    const int Lb   = ((w >> 2) << 5) + ((w & 3) << 2);   // L(w, 0)
    const int vwin = (w ^ (lane & 7)) << 3;
    float vr[8];
    #pragma unroll
    for (int j = 0; j < 8; j++) {
        int L = Lb + ((j >> 2) << 4) + (j & 3);
        vr[j] = vh[((size_t)(ck * 64 + L)) * D_ + lane];   // coalesced b32
    }
    union { unsigned int u[4]; short8 s8; } pv;
    pv.u[0] = pk2(vr[0], vr[1]); pv.u[1] = pk2(vr[2], vr[3]);
    pv.u[2] = pk2(vr[4], vr[5]); pv.u[3] = pk2(vr[6], vr[7]);
    *(short8*)&vd[lane * 64 + vwin] = pv.s8;                             // b128
}

// ========================= kernel 2: attention ==============================
// 512 threads = 8 waves; wave = 64 queries (4 m-tiles); block = 512 queries;
// grid = 128 heads * 2 q-tiles (XCD-swizzled) -> 1 block/CU, 2 waves/SIMD.
__global__ __launch_bounds__(512, 2) void attn_fused2(
    const float* __restrict__ q,
    const unsigned short* __restrict__ kimg,
    const unsigned short* __restrict__ vimg,
    float* __restrict__ out)
{
    __shared__ __align__(16) unsigned short ks[4][64 * 64];
    __shared__ __align__(16) unsigned short vt[4][64 * 64];

    const int bid = blockIdx.x;
    const int xcd = bid & 7, rest = bid >> 3;
    const int qt = rest & 1;                   // 2 q-tiles per head
    const int head = (rest >> 1) * 8 + xcd;    // 2 blocks of a head share an XCD
    const int tid = threadIdx.x, w = tid >> 6, lane = tid & 63;
    const int lam = lane & 15, quad = lane >> 4;
    const int sw = lam & 7;                    // frag-read swizzle key
    const int q0 = qt * 512 + w * 64;          // this wave's 64 queries

    const float* qh = q + ((size_t)head * N_ + q0) * D_;
    const unsigned short* kih = kimg + (size_t)head * 16 * IMG_SHORTS;
    const unsigned short* vih = vimg + (size_t)head * 16 * IMG_SHORTS;

    // ---- Q: load f32, L2-normalize (x log2e), pack to bf16 B-frags ----
    short8 aq[4][2];
    #pragma unroll
    for (int t = 0; t < 4; t++) {
        const float* qr = qh + (t * 16 + lam) * D_ + quad * 8;
        float4 f0 = *(const float4*)(qr);
        float4 f1 = *(const float4*)(qr + 4);
        float4 f2 = *(const float4*)(qr + 32);
        float4 f3 = *(const float4*)(qr + 36);
        float ss = f0.x*f0.x + f0.y*f0.y + f0.z*f0.z + f0.w*f0.w
                 + f1.x*f1.x + f1.y*f1.y + f1.z*f1.z + f1.w*f1.w
                 + f2.x*f2.x + f2.y*f2.y + f2.z*f2.z + f2.w*f2.w
                 + f3.x*f3.x + f3.y*f3.y + f3.z*f3.z + f3.w*f3.w;
        ss += __shfl_xor(ss, 16);      // 4 quads of same lam cover dims 0..63
        ss += __shfl_xor(ss, 32);
        float sc = LOG2E * __ocml_native_rsqrt_f32(ss);
        union { unsigned int u[4]; short8 s8; } p0, p1;
        p0.u[0] = pk2(f0.x*sc, f0.y*sc); p0.u[1] = pk2(f0.z*sc, f0.w*sc);
        p0.u[2] = pk2(f1.x*sc, f1.y*sc); p0.u[3] = pk2(f1.z*sc, f1.w*sc);
        p1.u[0] = pk2(f2.x*sc, f2.y*sc); p1.u[1] = pk2(f2.z*sc, f2.w*sc);
        p1.u[2] = pk2(f3.x*sc, f3.y*sc); p1.u[3] = pk2(f3.z*sc, f3.w*sc);
        aq[t][0] = p0.s8; aq[t][1] = p1.s8;
    }

    floatx4 oacc[4][4];
    #pragma unroll
    for (int t = 0; t < 4; t++)
        #pragma unroll
        for (int dt = 0; dt < 4; dt++) oacc[t][dt] = (floatx4){0.f, 0.f, 0.f, 0.f};
    float l[4] = {0.f, 0.f, 0.f, 0.f};

    // ---- staging = pure DMA: 2x global_load_lds dwordx4 per thread/chunk ----
    unsigned short* ksbase = &ks[0][0];
    unsigned short* vtbase = &vt[0][0];
    auto stage_dma = [&](int buf, int ck) {
        const unsigned short* kg = kih + ck * IMG_SHORTS + tid * 8;
        const unsigned short* vg = vih + ck * IMG_SHORTS + tid * 8;
        unsigned short* kdst = ksbase + buf * IMG_SHORTS + w * 512;
        unsigned short* vdst = vtbase + buf * IMG_SHORTS + w * 512;
        __builtin_amdgcn_global_load_lds(
            reinterpret_cast<const unsigned int*>(kg),
            reinterpret_cast<unsigned int*>(kdst), 16, 0, 0);
        __builtin_amdgcn_global_load_lds(
            reinterpret_cast<const unsigned int*>(vg),
            reinterpret_cast<unsigned int*>(vdst), 16, 0, 0);
    };

    auto compute = [&](int buf) {
        const unsigned short* ksb = ksbase + buf * IMG_SHORTS;
        const unsigned short* vsb = vtbase + buf * IMG_SHORTS;
        #pragma unroll
        for (int g = 0; g < 2; g++) {
            // ---- S^T for 32 keys x 64 queries: A = K-frag (LDS), B = Q (regs) ----
            floatx4 s[4][2];
            #pragma unroll
            for (int s2 = 0; s2 < 2; s2++) {
                int st = g * 2 + s2;
                short8 bk0 = *(const short8*)(ksb + (st * 16 + lam) * 64 + (((0 + quad) ^ sw) << 3));
                short8 bk1 = *(const short8*)(ksb + (st * 16 + lam) * 64 + (((4 + quad) ^ sw) << 3));
                #pragma unroll
                for (int t = 0; t < 4; t++) {
                    floatx4 acc = (floatx4){0.f, 0.f, 0.f, 0.f};
                    acc = __builtin_amdgcn_mfma_f32_16x16x32_bf16(bk0, aq[t][0], acc, 0, 0, 0);
                    acc = __builtin_amdgcn_mfma_f32_16x16x32_bf16(bk1, aq[t][1], acc, 0, 0, 0);
                    s[t][s2] = acc;
                }
            }
            // ---- exp2 + pack: S^T C-layout IS the PV A-fragment layout ----
            short8 pa[4];
            #pragma unroll
            for (int t = 0; t < 4; t++) {
                float e00 = __ocml_native_exp2_f32(s[t][0][0]);
                float e01 = __ocml_native_exp2_f32(s[t][0][1]);
                float e02 = __ocml_native_exp2_f32(s[t][0][2]);
                float e03 = __ocml_native_exp2_f32(s[t][0][3]);
                float e10 = __ocml_native_exp2_f32(s[t][1][0]);
                float e11 = __ocml_native_exp2_f32(s[t][1][1]);
                float e12 = __ocml_native_exp2_f32(s[t][1][2]);
                float e13 = __ocml_native_exp2_f32(s[t][1][3]);
                l[t] += ((e00 + e01) + (e02 + e03)) + ((e10 + e11) + (e12 + e13));
                union { unsigned int u[4]; short8 s8; } pk;
                pk.u[0] = pk2(e00, e01); pk.u[1] = pk2(e02, e03);
                pk.u[2] = pk2(e10, e11); pk.u[3] = pk2(e12, e13);
                pa[t] = pk.s8;
            }
            // ---- PV: B-frag = one b128 from vt (permuted V^T) ----
            #pragma unroll
            for (int dt = 0; dt < 4; dt++) {
                short8 bv = *(const short8*)(vsb + (dt * 16 + lam) * 64 + (((g * 4 + quad) ^ sw) << 3));
                #pragma unroll
                for (int t = 0; t < 4; t++)
                    oacc[t][dt] = __builtin_amdgcn_mfma_f32_16x16x32_bf16(pa[t], bv, oacc[t][dt], 0, 0, 0);
            }
        }
    };

    // ---- counted-vmcnt pipeline: 1 raw barrier per chunk, DMAs for chunks
    //      c+1,c+2 stay in flight across it (never vmcnt(0) mid-loop) ----
    stage_dma(0, 0);
    stage_dma(1, 1);
    for (int c = 0; c < 16; ++c) {
        if (c < 14) {
            stage_dma((c + 2) & 3, c + 2);
            asm volatile("s_waitcnt vmcnt(4)" ::: "memory");  // chunk c landed
        } else if (c == 14) {
            asm volatile("s_waitcnt vmcnt(2)" ::: "memory");
        } else {
            asm volatile("s_waitcnt vmcnt(0)" ::: "memory");
        }
        __builtin_amdgcn_sched_barrier(0);
        __builtin_amdgcn_s_barrier();
        compute(c & 3);
    }

    // ---- epilogue: reduce l across quads, divide, store f32 ----
    const int b = head >> 4, hh = head & 15;
    #pragma unroll
    for (int t = 0; t < 4; t++) {
        float lr = l[t];
        lr += __shfl_xor(lr, 16);
        lr += __shfl_xor(lr, 32);
        float rl = 1.0f / lr;                    // lane lam holds 1/l for query t*16+lam
        float rq[4];
        #pragma unroll
        for (int r = 0; r < 4; r++) rq[r] = __shfl(rl, quad * 4 + r);
        float* ob = out + ((size_t)b * N_ + q0 + t * 16) * (H_ * D_) + hh * 64;
        #pragma unroll
        for (int dt = 0; dt < 4; dt++)
            #pragma unroll
            for (int r = 0; r < 4; r++)
                ob[(quad * 4 + r) * (H_ * D_) + dt * 16 + lam] = oacc[t][dt][r] * rq[r];
    }
}

// ===================== fallback: R5 fused kernel ============================
__global__ __launch_bounds__(512, 4) void attn_fused(
    const float* __restrict__ q, const float* __restrict__ k,
    const float* __restrict__ v, float* __restrict__ out)
{
    __shared__ __align__(16) unsigned short ks[2][64 * 64];
    __shared__ __align__(16) unsigned short vt[2][64 * 64];

    const int bid = blockIdx.x;
    const int xcd = bid & 7, rest = bid >> 3;
    const int qt = rest & 3;
    const int head = (rest >> 2) * 8 + xcd;
    const int tid = threadIdx.x, w = tid >> 6, lane = tid & 63;
    const int lam = lane & 15, quad = lane >> 4;
    const int sw = lam & 7;
    const int q0 = qt * 256 + w * 32;

    const float* qh = q + ((size_t)head * N_ + q0) * D_;
    const float* kh = k + (size_t)head * N_ * D_;
    const float* vh = v + (size_t)head * N_ * D_;

    short8 aq[2][2];
    #pragma unroll
    for (int t = 0; t < 2; t++) {
        const float* qr = qh + (t * 16 + lam) * D_ + quad * 8;
        float4 f0 = *(const float4*)(qr);
        float4 f1 = *(const float4*)(qr + 4);
        float4 f2 = *(const float4*)(qr + 32);
        float4 f3 = *(const float4*)(qr + 36);
        float ss = f0.x*f0.x + f0.y*f0.y + f0.z*f0.z + f0.w*f0.w
                 + f1.x*f1.x + f1.y*f1.y + f1.z*f1.z + f1.w*f1.w
                 + f2.x*f2.x + f2.y*f2.y + f2.z*f2.z + f2.w*f2.w
                 + f3.x*f3.x + f3.y*f3.y + f3.z*f3.z + f3.w*f3.w;
        ss += __shfl_xor(ss, 16);
        ss += __shfl_xor(ss, 32);
        float sc = LOG2E * __ocml_native_rsqrt_f32(ss);
        union { unsigned int u[4]; short8 s8; } p0, p1;
        p0.u[0] = pk2(f0.x*sc, f0.y*sc); p0.u[1] = pk2(f0.z*sc, f0.w*sc);
        p0.u[2] = pk2(f1.x*sc, f1.y*sc); p0.u[3] = pk2(f1.z*sc, f1.w*sc);
        p1.u[0] = pk2(f2.x*sc, f2.y*sc); p1.u[1] = pk2(f2.z*sc, f2.w*sc);
        p1.u[2] = pk2(f3.x*sc, f3.y*sc); p1.u[3] = pk2(f3.z*sc, f3.w*sc);
        aq[t][0] = p0.s8; aq[t][1] = p1.s8;
    }

    floatx4 oacc[2][4];
    #pragma unroll
    for (int t = 0; t < 2; t++)
        #pragma unroll
        for (int dt = 0; dt < 4; dt++) oacc[t][dt] = (floatx4){0.f, 0.f, 0.f, 0.f};
    float l[2] = {0.f, 0.f};

    const int srow = w * 8 + (lane >> 3);
    const int cbk  = lane & 7;
    const int ksw  = srow & 7;
    const int Lb   = ((w >> 2) << 5) + ((w & 3) << 2);
    const int vwin = (w ^ (lane & 7)) << 3;

    float4 kx[2];
    float  vr[8];

    auto gload = [&](int ck) {
        const float* kp = kh + ((size_t)(ck * 64 + srow)) * D_ + cbk * 8;
        kx[0] = *(const float4*)(kp);
        kx[1] = *(const float4*)(kp + 4);
        #pragma unroll
        for (int j = 0; j < 8; j++) {
            int L = Lb + ((j >> 2) << 4) + (j & 3);
            vr[j] = vh[((size_t)(ck * 64 + L)) * D_ + lane];
        }
    };

    auto stage = [&](int buf) {
        float ss = kx[0].x*kx[0].x + kx[0].y*kx[0].y + kx[0].z*kx[0].z + kx[0].w*kx[0].w
                 + kx[1].x*kx[1].x + kx[1].y*kx[1].y + kx[1].z*kx[1].z + kx[1].w*kx[1].w;
        ss += __shfl_xor(ss, 1);
        ss += __shfl_xor(ss, 2);
        ss += __shfl_xor(ss, 4);
        float sc = __ocml_native_rsqrt_f32(ss);
        union { unsigned int u[4]; short8 s8; } pk;
        pk.u[0] = pk2(kx[0].x*sc, kx[0].y*sc); pk.u[1] = pk2(kx[0].z*sc, kx[0].w*sc);
        pk.u[2] = pk2(kx[1].x*sc, kx[1].y*sc); pk.u[3] = pk2(kx[1].z*sc, kx[1].w*sc);
        *(short8*)&ks[buf][srow * 64 + ((cbk ^ ksw) << 3)] = pk.s8;
        union { unsigned int u[4]; short8 s8; } pv;
        pv.u[0] = pk2(vr[0], vr[1]); pv.u[1] = pk2(vr[2], vr[3]);
        pv.u[2] = pk2(vr[4], vr[5]); pv.u[3] = pk2(vr[6], vr[7]);
        *(short8*)&vt[buf][lane * 64 + vwin] = pv.s8;
    };

    auto compute = [&](int buf) {
        const unsigned short* ksb = &ks[buf][0];
        const unsigned short* vsb = &vt[buf][0];
        #pragma unroll
        for (int g = 0; g < 2; g++) {
            floatx4 s[2][2];
            #pragma unroll
            for (int s2 = 0; s2 < 2; s2++) {
                int st = g * 2 + s2;
                short8 bk0 = *(const short8*)(ksb + (st * 16 + lam) * 64 + (((0 + quad) ^ sw) << 3));
                short8 bk1 = *(const short8*)(ksb + (st * 16 + lam) * 64 + (((4 + quad) ^ sw) << 3));
                #pragma unroll
                for (int t = 0; t < 2; t++) {
                    floatx4 acc = (floatx4){0.f, 0.f, 0.f, 0.f};
                    acc = __builtin_amdgcn_mfma_f32_16x16x32_bf16(bk0, aq[t][0], acc, 0, 0, 0);
                    acc = __builtin_amdgcn_mfma_f32_16x16x32_bf16(bk1, aq[t][1], acc, 0, 0, 0);
                    s[t][s2] = acc;
                }
            }
            short8 pa[2];
            #pragma unroll
            for (int t = 0; t < 2; t++) {
                float e00 = __ocml_native_exp2_f32(s[t][0][0]);
                float e01 = __ocml_native_exp2_f32(s[t][0][1]);
                float e02 = __ocml_native_exp2_f32(s[t][0][2]);
                float e03 = __ocml_native_exp2_f32(s[t][0][3]);
                float e10 = __ocml_native_exp2_f32(s[t][1][0]);
                float e11 = __ocml_native_exp2_f32(s[t][1][1]);
                float e12 = __ocml_native_exp2_f32(s[t][1][2]);
                float e13 = __ocml_native_exp2_f32(s[t][1][3]);
                l[t] += ((e00 + e01) + (e02 + e03)) + ((e10 + e11) + (e12 + e13));
                union { unsigned int u[4]; short8 s8; } pk;
                pk.u[0] = pk2(e00, e01); pk.u[1] = pk2(e02, e03);
                pk.u[2] = pk2(e10, e11); pk.u[3] = pk2(e12, e13);
                pa[t] = pk.s8;
            }
            #pragma unroll
            for (int dt = 0; dt < 4; dt++) {
                short8 bv = *(const short8*)(vsb + (dt * 16 + lam) * 64 + (((g * 4 + quad) ^ sw) << 3));
                #pragma unroll
                for (int t = 0; t < 2; t++)
                    oacc[t][dt] = __builtin_amdgcn_mfma_f32_16x16x32_bf16(pa[t], bv, oacc[t][dt], 0, 0, 0);
            }
        }
    };

    gload(0);
    stage(0);
    __syncthreads();
    for (int c = 0; c < 16; ++c) {
        int buf = c & 1;
        if (c < 15) gload(c + 1);
        compute(buf);
        if (c < 15) stage(buf ^ 1);
        __syncthreads();
    }

    const int b = head >> 4, hh = head & 15;
    #pragma unroll
    for (int t = 0; t < 2; t++) {
        float lr = l[t];
        lr += __shfl_xor(lr, 16);
        lr += __shfl_xor(lr, 32);
        float rl = 1.0f / lr;
        float rq[4];
        #pragma unroll
        for (int r = 0; r < 4; r++) rq[r] = __shfl(rl, quad * 4 + r);
        float* ob = out + ((size_t)b * N_ + q0 + t * 16) * (H_ * D_) + hh * 64;
        #pragma unroll
        for (int dt = 0; dt < 4; dt++)
            #pragma unroll
            for (int r = 0; r < 4; r++)
                ob[(quad * 4 + r) * (H_ * D_) + dt * 16 + lam] = oacc[t][dt][r] * rq[r];
    }
}

extern "C" void kernel_launch(void* const* d_in, const int* in_sizes, int n_in,
                              void* d_out, int out_size, void* d_ws, size_t ws_size,
                              hipStream_t stream) {
    const float* q = (const float*)d_in[0];
    const float* k = (const float*)d_in[1];
    const float* v = (const float*)d_in[2];
    float* out = (float*)d_out;
    const size_t need = (size_t)NH_ * NCHUNK * IMG_SHORTS * 2 * sizeof(unsigned short); // 32 MB
    if (d_ws != nullptr && ws_size >= need) {
        unsigned short* kimg = (unsigned short*)d_ws;
        unsigned short* vimg = kimg + (size_t)NH_ * NCHUNK * IMG_SHORTS;
        hipLaunchKernelGGL(prep_kv, dim3(NH_ * NCHUNK), dim3(512), 0, stream, k, v, kimg, vimg);
        hipLaunchKernelGGL(attn_fused2, dim3(NH_ * 2), dim3(512), 0, stream, q, kimg, vimg, out);
    } else {
        hipLaunchKernelGGL(attn_fused, dim3(NH_ * 4), dim3(512), 0, stream, q, k, v, out);
    }
}

// Round 11
// 166.793 us; speedup vs baseline: 1.0046x; 1.0046x over previous
//
#include <hip/hip_runtime.h>
#include <stdint.h>

typedef __attribute__((ext_vector_type(8))) short short8;
typedef __attribute__((ext_vector_type(4))) float floatx4;

#define B_   8
#define H_   16
#define N_   1024
#define D_   64
#define NH_  (B_*H_)
#define LOG2E 1.44269504088896340736f
#define IMG_SHORTS 4096          // 64*64 shorts = 8192 B per (head,chunk) image
#define NCHUNK 16

extern "C" {
__device__ float __ocml_native_exp2_f32(float);
__device__ float __ocml_native_rsqrt_f32(float);
}

// pack two f32 -> bf16x2 (round-half-up on magnitude; fine for our ranges)
__device__ __forceinline__ unsigned int pk2(float a, float b) {
    unsigned int ua = __float_as_uint(a) + 0x8000u;
    unsigned int ub = __float_as_uint(b) + 0x8000u;
    return __builtin_amdgcn_perm(ub, ua, 0x07060302);  // (bf(b)<<16)|bf(a)
}

// ---------------------------------------------------------------------------
// R11: revert to R9 config (32q/wave, grid 512, 4 LDS buffers -- best attn,
// 50.1 us; R10's 64q/wave was 54.5: LDS traffic NOT binding, TLP loss hurt).
// Changes: (a) barrier every 2 chunks (8 barriers, was 16): barrier first,
// then pair-stage chunks c+2,c+3 (WAR-safe: they overwrite bufs (c-2)&3,
// (c-1)&3 whose computes finished before this rendezvous), steady vmcnt(4);
// single compute call site (anti-spill: R8's duplicated bodies spilled).
// (b) prep_kv grid XCD-matched to attn's head mapping (head&7 == xcd) so
// images are produced in the same XCD L2 that consumes them.
// setprio: permanently removed (~60% regression, R1 vs R5 A/B).
// Spill gate: WRITE_SIZE must stay ~33 MB, VGPR ~64.
// ---------------------------------------------------------------------------

// ============================ kernel 1: prep ================================
// grid = 2048 blocks; xcd = bid&7; head = (idx>>4)*8 + xcd  ->  head&7 == xcd,
// matching attn's head mapping (same-XCD L2 production/consumption).
__global__ __launch_bounds__(512) void prep_kv(
    const float* __restrict__ k, const float* __restrict__ v,
    unsigned short* __restrict__ kimg, unsigned short* __restrict__ vimg)
{
    const int bid = blockIdx.x;
    const int xcd = bid & 7;
    const int idx = bid >> 3;            // 0..255
    const int ck  = idx & 15;
    const int head = (idx >> 4) * 8 + xcd;
    const int tid = threadIdx.x, w = tid >> 6, lane = tid & 63;

    const float* kh = k + (size_t)head * N_ * D_;
    const float* vh = v + (size_t)head * N_ * D_;
    unsigned short* kd = kimg + ((size_t)(head * 16 + ck)) * IMG_SHORTS;
    unsigned short* vd = vimg + ((size_t)(head * 16 + ck)) * IMG_SHORTS;

    // K: thread owns key-row srow, 8 dims at d-block cbk = lane&7
    const int srow = w * 8 + (lane >> 3);
    const int cbk  = lane & 7;
    const int ksw  = srow & 7;
    const float* kp = kh + ((size_t)(ck * 64 + srow)) * D_ + cbk * 8;
    float4 kx0 = *(const float4*)(kp);
    float4 kx1 = *(const float4*)(kp + 4);
    float ss = kx0.x*kx0.x + kx0.y*kx0.y + kx0.z*kx0.z + kx0.w*kx0.w
             + kx1.x*kx1.x + kx1.y*kx1.y + kx1.z*kx1.z + kx1.w*kx1.w;
    ss += __shfl_xor(ss, 1);       // 8 lanes of same key cover dims 0..63
    ss += __shfl_xor(ss, 2);
    ss += __shfl_xor(ss, 4);
    float sc = __ocml_native_rsqrt_f32(ss);
    union { unsigned int u[4]; short8 s8; } pk;
    pk.u[0] = pk2(kx0.x*sc, kx0.y*sc); pk.u[1] = pk2(kx0.z*sc, kx0.w*sc);
    pk.u[2] = pk2(kx1.x*sc, kx1.y*sc); pk.u[3] = pk2(kx1.z*sc, kx1.w*sc);
    *(short8*)&kd[srow * 64 + ((cbk ^ ksw) << 3)] = pk.s8;               // b128

    // V^T: thread owns d = lane, phys key-block cb = w (8 logical keys)
    const int Lb   = ((w >> 2) << 5) + ((w & 3) << 2);   // L(w, 0)
    const int vwin = (w ^ (lane & 7)) << 3;
    float vr[8];
    #pragma unroll
    for (int j = 0; j < 8; j++) {
        int L = Lb + ((j >> 2) << 4) + (j & 3);
        vr[j] = vh[((size_t)(ck * 64 + L)) * D_ + lane];   // coalesced b32
    }
    union { unsigned int u[4]; short8 s8; } pv;
    pv.u[0] = pk2(vr[0], vr[1]); pv.u[1] = pk2(vr[2], vr[3]);
    pv.u[2] = pk2(vr[4], vr[5]); pv.u[3] = pk2(vr[6], vr[7]);
    *(short8*)&vd[lane * 64 + vwin] = pv.s8;                             // b128
}

// ========================= kernel 2: attention ==============================
// 512 threads = 8 waves; wave = 32 queries; block = 256 queries;
// grid = 128 heads * 4 q-tiles (XCD-swizzled) -> 2 blocks/CU, 4 waves/SIMD.
__global__ __launch_bounds__(512, 4) void attn_fused2(
    const float* __restrict__ q,
    const unsigned short* __restrict__ kimg,
    const unsigned short* __restrict__ vimg,
    float* __restrict__ out)
{
    __shared__ __align__(16) unsigned short ks[4][64 * 64];
    __shared__ __align__(16) unsigned short vt[4][64 * 64];

    const int bid = blockIdx.x;
    const int xcd = bid & 7, rest = bid >> 3;
    const int qt = rest & 3;
    const int head = (rest >> 2) * 8 + xcd;    // 4 blocks of a head share an XCD
    const int tid = threadIdx.x, w = tid >> 6, lane = tid & 63;
    const int lam = lane & 15, quad = lane >> 4;
    const int sw = lam & 7;                    // frag-read swizzle key
    const int q0 = qt * 256 + w * 32;          // this wave's 32 queries

    const float* qh = q + ((size_t)head * N_ + q0) * D_;
    const unsigned short* kih = kimg + (size_t)head * 16 * IMG_SHORTS;
    const unsigned short* vih = vimg + (size_t)head * 16 * IMG_SHORTS;

    // ---- Q: load f32, L2-normalize (x log2e), pack to bf16 B-frags ----
    short8 aq[2][2];
    #pragma unroll
    for (int t = 0; t < 2; t++) {
        const float* qr = qh + (t * 16 + lam) * D_ + quad * 8;
        float4 f0 = *(const float4*)(qr);
        float4 f1 = *(const float4*)(qr + 4);
        float4 f2 = *(const float4*)(qr + 32);
        float4 f3 = *(const float4*)(qr + 36);
        float ss = f0.x*f0.x + f0.y*f0.y + f0.z*f0.z + f0.w*f0.w
                 + f1.x*f1.x + f1.y*f1.y + f1.z*f1.z + f1.w*f1.w
                 + f2.x*f2.x + f2.y*f2.y + f2.z*f2.z + f2.w*f2.w
                 + f3.x*f3.x + f3.y*f3.y + f3.z*f3.z + f3.w*f3.w;
        ss += __shfl_xor(ss, 16);      // 4 quads of same lam cover dims 0..63
        ss += __shfl_xor(ss, 32);
        float sc = LOG2E * __ocml_native_rsqrt_f32(ss);
        union { unsigned int u[4]; short8 s8; } p0, p1;
        p0.u[0] = pk2(f0.x*sc, f0.y*sc); p0.u[1] = pk2(f0.z*sc, f0.w*sc);
        p0.u[2] = pk2(f1.x*sc, f1.y*sc); p0.u[3] = pk2(f1.z*sc, f1.w*sc);
        p1.u[0] = pk2(f2.x*sc, f2.y*sc); p1.u[1] = pk2(f2.z*sc, f2.w*sc);
        p1.u[2] = pk2(f3.x*sc, f3.y*sc); p1.u[3] = pk2(f3.z*sc, f3.w*sc);
        aq[t][0] = p0.s8; aq[t][1] = p1.s8;
    }

    floatx4 oacc[2][4];
    #pragma unroll
    for (int t = 0; t < 2; t++)
        #pragma unroll
        for (int dt = 0; dt < 4; dt++) oacc[t][dt] = (floatx4){0.f, 0.f, 0.f, 0.f};
    float l[2] = {0.f, 0.f};

    // ---- staging = pure DMA: 2x global_load_lds dwordx4 per thread/chunk ----
    unsigned short* ksbase = &ks[0][0];
    unsigned short* vtbase = &vt[0][0];
    auto stage_dma = [&](int buf, int ck) {
        const unsigned short* kg = kih + ck * IMG_SHORTS + tid * 8;
        const unsigned short* vg = vih + ck * IMG_SHORTS + tid * 8;
        unsigned short* kdst = ksbase + buf * IMG_SHORTS + w * 512;
        unsigned short* vdst = vtbase + buf * IMG_SHORTS + w * 512;
        __builtin_amdgcn_global_load_lds(
            reinterpret_cast<const unsigned int*>(kg),
            reinterpret_cast<unsigned int*>(kdst), 16, 0, 0);
        __builtin_amdgcn_global_load_lds(
            reinterpret_cast<const unsigned int*>(vg),
            reinterpret_cast<unsigned int*>(vdst), 16, 0, 0);
    };

    auto compute = [&](int buf) {
        const unsigned short* ksb = ksbase + buf * IMG_SHORTS;
        const unsigned short* vsb = vtbase + buf * IMG_SHORTS;
        #pragma unroll
        for (int g = 0; g < 2; g++) {
            // ---- S^T for 32 keys: A = K-frag (LDS b128), B = Q-frag (regs) ----
            floatx4 s[2][2];
            #pragma unroll
            for (int s2 = 0; s2 < 2; s2++) {
                int st = g * 2 + s2;
                short8 bk0 = *(const short8*)(ksb + (st * 16 + lam) * 64 + (((0 + quad) ^ sw) << 3));
                short8 bk1 = *(const short8*)(ksb + (st * 16 + lam) * 64 + (((4 + quad) ^ sw) << 3));
                #pragma unroll
                for (int t = 0; t < 2; t++) {
                    floatx4 acc = (floatx4){0.f, 0.f, 0.f, 0.f};
                    acc = __builtin_amdgcn_mfma_f32_16x16x32_bf16(bk0, aq[t][0], acc, 0, 0, 0);
                    acc = __builtin_amdgcn_mfma_f32_16x16x32_bf16(bk1, aq[t][1], acc, 0, 0, 0);
                    s[t][s2] = acc;
                }
            }
            // ---- exp2 + pack: S^T C-layout IS the PV A-fragment layout ----
            short8 pa[2];
            #pragma unroll
            for (int t = 0; t < 2; t++) {
                float e00 = __ocml_native_exp2_f32(s[t][0][0]);
                float e01 = __ocml_native_exp2_f32(s[t][0][1]);
                float e02 = __ocml_native_exp2_f32(s[t][0][2]);
                float e03 = __ocml_native_exp2_f32(s[t][0][3]);
                float e10 = __ocml_native_exp2_f32(s[t][1][0]);
                float e11 = __ocml_native_exp2_f32(s[t][1][1]);
                float e12 = __ocml_native_exp2_f32(s[t][1][2]);
                float e13 = __ocml_native_exp2_f32(s[t][1][3]);
                l[t] += ((e00 + e01) + (e02 + e03)) + ((e10 + e11) + (e12 + e13));
                union { unsigned int u[4]; short8 s8; } pk;
                pk.u[0] = pk2(e00, e01); pk.u[1] = pk2(e02, e03);
                pk.u[2] = pk2(e10, e11); pk.u[3] = pk2(e12, e13);
                pa[t] = pk.s8;
            }
            // ---- PV: B-frag = one b128 from vt (permuted V^T) ----
            #pragma unroll
            for (int dt = 0; dt < 4; dt++) {
                short8 bv = *(const short8*)(vsb + (dt * 16 + lam) * 64 + (((g * 4 + quad) ^ sw) << 3));
                #pragma unroll
                for (int t = 0; t < 2; t++)
                    oacc[t][dt] = __builtin_amdgcn_mfma_f32_16x16x32_bf16(pa[t], bv, oacc[t][dt], 0, 0, 0);
            }
        }
    };

    // ---- pair-barrier counted-vmcnt pipeline: barrier every 2 chunks.
    //      At even c: barrier, then stage (c+2,c+3) (overwrites bufs of
    //      chunks c-2,c-1, whose computes finished before this rendezvous),
    //      then vmcnt(4) (only c+2,c+3's 4 loads outstanding -> c,c+1 landed).
    stage_dma(0, 0);
    stage_dma(1, 1);
    for (int c = 0; c < 16; ++c) {
        if ((c & 1) == 0) {
            __builtin_amdgcn_s_barrier();
            if (c < 14) {
                stage_dma((c + 2) & 3, c + 2);
                stage_dma((c + 3) & 3, c + 3);
                asm volatile("s_waitcnt vmcnt(4)" ::: "memory");
            } else {
                asm volatile("s_waitcnt vmcnt(0)" ::: "memory");
            }
            __builtin_amdgcn_sched_barrier(0);
        }
        compute(c & 3);
    }

    // ---- epilogue: reduce l across quads, divide, store f32 ----
    const int b = head >> 4, hh = head & 15;
    #pragma unroll
    for (int t = 0; t < 2; t++) {
        float lr = l[t];
        lr += __shfl_xor(lr, 16);
        lr += __shfl_xor(lr, 32);
        float rl = 1.0f / lr;                    // lane lam holds 1/l for query t*16+lam
        float rq[4];
        #pragma unroll
        for (int r = 0; r < 4; r++) rq[r] = __shfl(rl, quad * 4 + r);
        float* ob = out + ((size_t)b * N_ + q0 + t * 16) * (H_ * D_) + hh * 64;
        #pragma unroll
        for (int dt = 0; dt < 4; dt++)
            #pragma unroll
            for (int r = 0; r < 4; r++)
                ob[(quad * 4 + r) * (H_ * D_) + dt * 16 + lam] = oacc[t][dt][r] * rq[r];
    }
}

// ===================== fallback: R5 fused kernel ============================
__global__ __launch_bounds__(512, 4) void attn_fused(
    const float* __restrict__ q, const float* __restrict__ k,
    const float* __restrict__ v, float* __restrict__ out)
{
    __shared__ __align__(16) unsigned short ks[2][64 * 64];
    __shared__ __align__(16) unsigned short vt[2][64 * 64];

    const int bid = blockIdx.x;
    const int xcd = bid & 7, rest = bid >> 3;
    const int qt = rest & 3;
    const int head = (rest >> 2) * 8 + xcd;
    const int tid = threadIdx.x, w = tid >> 6, lane = tid & 63;
    const int lam = lane & 15, quad = lane >> 4;
    const int sw = lam & 7;
    const int q0 = qt * 256 + w * 32;

    const float* qh = q + ((size_t)head * N_ + q0) * D_;
    const float* kh = k + (size_t)head * N_ * D_;
    const float* vh = v + (size_t)head * N_ * D_;

    short8 aq[2][2];
    #pragma unroll
    for (int t = 0; t < 2; t++) {
        const float* qr = qh + (t * 16 + lam) * D_ + quad * 8;
        float4 f0 = *(const float4*)(qr);
        float4 f1 = *(const float4*)(qr + 4);
        float4 f2 = *(const float4*)(qr + 32);
        float4 f3 = *(const float4*)(qr + 36);
        float ss = f0.x*f0.x + f0.y*f0.y + f0.z*f0.z + f0.w*f0.w
                 + f1.x*f1.x + f1.y*f1.y + f1.z*f1.z + f1.w*f1.w
                 + f2.x*f2.x + f2.y*f2.y + f2.z*f2.z + f2.w*f2.w
                 + f3.x*f3.x + f3.y*f3.y + f3.z*f3.z + f3.w*f3.w;
        ss += __shfl_xor(ss, 16);
        ss += __shfl_xor(ss, 32);
        float sc = LOG2E * __ocml_native_rsqrt_f32(ss);
        union { unsigned int u[4]; short8 s8; } p0, p1;
        p0.u[0] = pk2(f0.x*sc, f0.y*sc); p0.u[1] = pk2(f0.z*sc, f0.w*sc);
        p0.u[2] = pk2(f1.x*sc, f1.y*sc); p0.u[3] = pk2(f1.z*sc, f1.w*sc);
        p1.u[0] = pk2(f2.x*sc, f2.y*sc); p1.u[1] = pk2(f2.z*sc, f2.w*sc);
        p1.u[2] = pk2(f3.x*sc, f3.y*sc); p1.u[3] = pk2(f3.z*sc, f3.w*sc);
        aq[t][0] = p0.s8; aq[t][1] = p1.s8;
    }

    floatx4 oacc[2][4];
    #pragma unroll
    for (int t = 0; t < 2; t++)
        #pragma unroll
        for (int dt = 0; dt < 4; dt++) oacc[t][dt] = (floatx4){0.f, 0.f, 0.f, 0.f};
    float l[2] = {0.f, 0.f};

    const int srow = w * 8 + (lane >> 3);
    const int cbk  = lane & 7;
    const int ksw  = srow & 7;
    const int Lb   = ((w >> 2) << 5) + ((w & 3) << 2);
    const int vwin = (w ^ (lane & 7)) << 3;

    float4 kx[2];
    float  vr[8];

    auto gload = [&](int ck) {
        const float* kp = kh + ((size_t)(ck * 64 + srow)) * D_ + cbk * 8;
        kx[0] = *(const float4*)(kp);
        kx[1] = *(const float4*)(kp + 4);
        #pragma unroll
        for (int j = 0; j < 8; j++) {
            int L = Lb + ((j >> 2) << 4) + (j & 3);
            vr[j] = vh[((size_t)(ck * 64 + L)) * D_ + lane];
        }
    };

    auto stage = [&](int buf) {
        float ss = kx[0].x*kx[0].x + kx[0].y*kx[0].y + kx[0].z*kx[0].z + kx[0].w*kx[0].w
                 + kx[1].x*kx[1].x + kx[1].y*kx[1].y + kx[1].z*kx[1].z + kx[1].w*kx[1].w;
        ss += __shfl_xor(ss, 1);
        ss += __shfl_xor(ss, 2);
        ss += __shfl_xor(ss, 4);
        float sc = __ocml_native_rsqrt_f32(ss);
        union { unsigned int u[4]; short8 s8; } pk;
        pk.u[0] = pk2(kx[0].x*sc, kx[0].y*sc); pk.u[1] = pk2(kx[0].z*sc, kx[0].w*sc);
        pk.u[2] = pk2(kx[1].x*sc, kx[1].y*sc); pk.u[3] = pk2(kx[1].z*sc, kx[1].w*sc);
        *(short8*)&ks[buf][srow * 64 + ((cbk ^ ksw) << 3)] = pk.s8;
        union { unsigned int u[4]; short8 s8; } pv;
        pv.u[0] = pk2(vr[0], vr[1]); pv.u[1] = pk2(vr[2], vr[3]);
        pv.u[2] = pk2(vr[4], vr[5]); pv.u[3] = pk2(vr[6], vr[7]);
        *(short8*)&vt[buf][lane * 64 + vwin] = pv.s8;
    };

    auto compute = [&](int buf) {
        const unsigned short* ksb = &ks[buf][0];
        const unsigned short* vsb = &vt[buf][0];
        #pragma unroll
        for (int g = 0; g < 2; g++) {
            floatx4 s[2][2];
            #pragma unroll
            for (int s2 = 0; s2 < 2; s2++) {
                int st = g * 2 + s2;
                short8 bk0 = *(const short8*)(ksb + (st * 16 + lam) * 64 + (((0 + quad) ^ sw) << 3));
                short8 bk1 = *(const short8*)(ksb + (st * 16 + lam) * 64 + (((4 + quad) ^ sw) << 3));
                #pragma unroll
                for (int t = 0; t < 2; t++) {
                    floatx4 acc = (floatx4){0.f, 0.f, 0.f, 0.f};
                    acc = __builtin_amdgcn_mfma_f32_16x16x32_bf16(bk0, aq[t][0], acc, 0, 0, 0);
                    acc = __builtin_amdgcn_mfma_f32_16x16x32_bf16(bk1, aq[t][1], acc, 0, 0, 0);
                    s[t][s2] = acc;
                }
            }
            short8 pa[2];
            #pragma unroll
            for (int t = 0; t < 2; t++) {
                float e00 = __ocml_native_exp2_f32(s[t][0][0]);
                float e01 = __ocml_native_exp2_f32(s[t][0][1]);
                float e02 = __ocml_native_exp2_f32(s[t][0][2]);
                float e03 = __ocml_native_exp2_f32(s[t][0][3]);
                float e10 = __ocml_native_exp2_f32(s[t][1][0]);
                float e11 = __ocml_native_exp2_f32(s[t][1][1]);
                float e12 = __ocml_native_exp2_f32(s[t][1][2]);
                float e13 = __ocml_native_exp2_f32(s[t][1][3]);
                l[t] += ((e00 + e01) + (e02 + e03)) + ((e10 + e11) + (e12 + e13));
                union { unsigned int u[4]; short8 s8; } pk;
                pk.u[0] = pk2(e00, e01); pk.u[1] = pk2(e02, e03);
                pk.u[2] = pk2(e10, e11); pk.u[3] = pk2(e12, e13);
                pa[t] = pk.s8;
            }
            #pragma unroll
            for (int dt = 0; dt < 4; dt++) {
                short8 bv = *(const short8*)(vsb + (dt * 16 + lam) * 64 + (((g * 4 + quad) ^ sw) << 3));
                #pragma unroll
                for (int t = 0; t < 2; t++)
                    oacc[t][dt] = __builtin_amdgcn_mfma_f32_16x16x32_bf16(pa[t], bv, oacc[t][dt], 0, 0, 0);
            }
        }
    };

    gload(0);
    stage(0);
    __syncthreads();
    for (int c = 0; c < 16; ++c) {
        int buf = c & 1;
        if (c < 15) gload(c + 1);
        compute(buf);
        if (c < 15) stage(buf ^ 1);
        __syncthreads();
    }

    const int b = head >> 4, hh = head & 15;
    #pragma unroll
    for (int t = 0; t < 2; t++) {
        float lr = l[t];
        lr += __shfl_xor(lr, 16);
        lr += __shfl_xor(lr, 32);
        float rl = 1.0f / lr;
        float rq[4];
        #pragma unroll
        for (int r = 0; r < 4; r++) rq[r] = __shfl(rl, quad * 4 + r);
        float* ob = out + ((size_t)b * N_ + q0 + t * 16) * (H_ * D_) + hh * 64;
        #pragma unroll
        for (int dt = 0; dt < 4; dt++)
            #pragma unroll
            for (int r = 0; r < 4; r++)
                ob[(quad * 4 + r) * (H_ * D_) + dt * 16 + lam] = oacc[t][dt][r] * rq[r];
    }
}

extern "C" void kernel_launch(void* const* d_in, const int* in_sizes, int n_in,
                              void* d_out, int out_size, void* d_ws, size_t ws_size,
                              hipStream_t stream) {
    const float* q = (const float*)d_in[0];
    const float* k = (const float*)d_in[1];
    const float* v = (const float*)d_in[2];
    float* out = (float*)d_out;
    const size_t need = (size_t)NH_ * NCHUNK * IMG_SHORTS * 2 * sizeof(unsigned short); // 32 MB
    if (d_ws != nullptr && ws_size >= need) {
        unsigned short* kimg = (unsigned short*)d_ws;
        unsigned short* vimg = kimg + (size_t)NH_ * NCHUNK * IMG_SHORTS;
        hipLaunchKernelGGL(prep_kv, dim3(NH_ * NCHUNK), dim3(512), 0, stream, k, v, kimg, vimg);
        hipLaunchKernelGGL(attn_fused2, dim3(NH_ * 4), dim3(512), 0, stream, q, kimg, vimg, out);
    } else {
        hipLaunchKernelGGL(attn_fused, dim3(NH_ * 4), dim3(512), 0, stream, q, k, v, out);
    }
}

// Round 12
// 158.240 us; speedup vs baseline: 1.0589x; 1.0541x over previous
//
#include <hip/hip_runtime.h>
#include <stdint.h>

typedef __attribute__((ext_vector_type(8))) short short8;
typedef __attribute__((ext_vector_type(4))) float floatx4;

#define B_   8
#define H_   16
#define N_   1024
#define D_   64
#define NH_  (B_*H_)
#define LOG2E 1.44269504088896340736f

extern "C" {
__device__ float __ocml_native_exp2_f32(float);
__device__ float __ocml_native_rsqrt_f32(float);
}

// pack two f32 -> bf16x2 (round-half-up on magnitude; fine for our ranges)
__device__ __forceinline__ unsigned int pk2(float a, float b) {
    unsigned int ua = __float_as_uint(a) + 0x8000u;
    unsigned int ub = __float_as_uint(b) + 0x8000u;
    return __builtin_amdgcn_perm(ub, ua, 0x07060302);  // (bf(b)<<16)|bf(a)
}

// ---------------------------------------------------------------------------
// FINAL (R12) = R5: the session's measured-best configuration (160.8 us
// harness / 67.5 us rocprof; prior session 159.1).
//
// Session evidence for why this exact form is the floor of this structure:
//  - setprio around MFMA: -60% here (barrier-locked waves; R1 vs R5 A/B).
//    NEVER re-add.
//  - 2x occupancy via grid (R3): -7%. 64q fat waves + ILP (R10): -9%.
//  - prep/attn split with DMA staging (R7-R11): attn alone 67.5->50 us but
//    prep (~16 us, HBM-bound) + 2nd launch makes harness WORSE (164-168).
//    Staging VALU is already latency-hidden in this fused kernel's bubbles.
//  - Counted-vmcnt / barrier-halving / pair-staging (R9/R11): +4% once,
//    then flat. Convoy family exhausted.
//  - Deeper in-register pipelining (R4/R6/R8): spills every time (no VGPR
//    headroom at 64-VGPR/4-wave point; pointer-args/duplicated bodies ->
//    scratch, up to 1.6 GB).
// Remaining state: no pipe >40% (VALU 37, MfmaUtil 19, HBM 17, conflicts 0)
// -- latency-bound on the per-chunk dependent chain, not a throughput
// roofline. Breaking it requires register headroom this tiling doesn't have.
//
// Structure: 512 threads = 8 waves; wave = 32 queries (2 m-tiles);
// block = 256 queries; grid = 128 heads * 4 (XCD-swizzled).
// LDS: stride-64-short rows, XOR swizzle cb^(row&7) on 16B blocks, all
// accesses 16B-aligned b128 (zero bank conflicts, measured).
//   ks[key][d] : K chunk bf16, row-normalized
//   vt[d][key] : V chunk transposed, key order permuted by
//                L(cb,j) = (cb>>2)*32 + (cb&3)*4 + (j>>2)*16 + (j&3)
// S^T = K.Qn^T via MFMA so exp(S^T) is directly the PV A-fragment.
// ---------------------------------------------------------------------------
__global__ __launch_bounds__(512, 4) void attn_fused(
    const float* __restrict__ q, const float* __restrict__ k,
    const float* __restrict__ v, float* __restrict__ out)
{
    __shared__ __align__(16) unsigned short ks[2][64 * 64];
    __shared__ __align__(16) unsigned short vt[2][64 * 64];

    const int bid = blockIdx.x;
    const int xcd = bid & 7, rest = bid >> 3;
    const int qt = rest & 3;
    const int head = (rest >> 2) * 8 + xcd;    // 4 blocks of a head share an XCD
    const int tid = threadIdx.x, w = tid >> 6, lane = tid & 63;
    const int lam = lane & 15, quad = lane >> 4;
    const int sw = lam & 7;                    // frag-read swizzle key
    const int q0 = qt * 256 + w * 32;          // this wave's 32 queries

    const float* qh = q + ((size_t)head * N_ + q0) * D_;
    const float* kh = k + (size_t)head * N_ * D_;
    const float* vh = v + (size_t)head * N_ * D_;

    // ---- Q: load f32, L2-normalize (x log2e), pack to bf16 B-frags ----
    short8 aq[2][2];
    #pragma unroll
    for (int t = 0; t < 2; t++) {
        const float* qr = qh + (t * 16 + lam) * D_ + quad * 8;
        float4 f0 = *(const float4*)(qr);
        float4 f1 = *(const float4*)(qr + 4);
        float4 f2 = *(const float4*)(qr + 32);
        float4 f3 = *(const float4*)(qr + 36);
        float ss = f0.x*f0.x + f0.y*f0.y + f0.z*f0.z + f0.w*f0.w
                 + f1.x*f1.x + f1.y*f1.y + f1.z*f1.z + f1.w*f1.w
                 + f2.x*f2.x + f2.y*f2.y + f2.z*f2.z + f2.w*f2.w
                 + f3.x*f3.x + f3.y*f3.y + f3.z*f3.z + f3.w*f3.w;
        ss += __shfl_xor(ss, 16);      // 4 quads of same lam cover dims 0..63
        ss += __shfl_xor(ss, 32);
        float sc = LOG2E * __ocml_native_rsqrt_f32(ss);
        union { unsigned int u[4]; short8 s8; } p0, p1;
        p0.u[0] = pk2(f0.x*sc, f0.y*sc); p0.u[1] = pk2(f0.z*sc, f0.w*sc);
        p0.u[2] = pk2(f1.x*sc, f1.y*sc); p0.u[3] = pk2(f1.z*sc, f1.w*sc);
        p1.u[0] = pk2(f2.x*sc, f2.y*sc); p1.u[1] = pk2(f2.z*sc, f2.w*sc);
        p1.u[2] = pk2(f3.x*sc, f3.y*sc); p1.u[3] = pk2(f3.z*sc, f3.w*sc);
        aq[t][0] = p0.s8; aq[t][1] = p1.s8;
    }

    floatx4 oacc[2][4];
    #pragma unroll
    for (int t = 0; t < 2; t++)
        #pragma unroll
        for (int dt = 0; dt < 4; dt++) oacc[t][dt] = (floatx4){0.f, 0.f, 0.f, 0.f};
    float l[2] = {0.f, 0.f};

    // ---- staging maps (512 threads stage one 64-key chunk) ----
    // K: thread owns key-row srow, 8 dims at d-block cbk = lane&7
    const int srow = w * 8 + (lane >> 3);
    const int cbk  = lane & 7;
    const int ksw  = srow & 7;
    // V^T: thread owns d = lane, phys key-block cb = w (8 logical keys)
    const int Lb   = ((w >> 2) << 5) + ((w & 3) << 2);   // L(w, 0)
    const int vwin = (w ^ (lane & 7)) << 3;

    float4 kx[2];
    float  vr[8];

    auto gload = [&](int ck) {
        const float* kp = kh + ((size_t)(ck * 64 + srow)) * D_ + cbk * 8;
        kx[0] = *(const float4*)(kp);
        kx[1] = *(const float4*)(kp + 4);
        #pragma unroll
        for (int j = 0; j < 8; j++) {
            int L = Lb + ((j >> 2) << 4) + (j & 3);
            vr[j] = vh[((size_t)(ck * 64 + L)) * D_ + lane];   // coalesced b32
        }
    };

    auto stage = [&](int buf) {
        float ss = kx[0].x*kx[0].x + kx[0].y*kx[0].y + kx[0].z*kx[0].z + kx[0].w*kx[0].w
                 + kx[1].x*kx[1].x + kx[1].y*kx[1].y + kx[1].z*kx[1].z + kx[1].w*kx[1].w;
        ss += __shfl_xor(ss, 1);       // 8 lanes of same key cover dims 0..63
        ss += __shfl_xor(ss, 2);
        ss += __shfl_xor(ss, 4);
        float sc = __ocml_native_rsqrt_f32(ss);
        union { unsigned int u[4]; short8 s8; } pk;
        pk.u[0] = pk2(kx[0].x*sc, kx[0].y*sc); pk.u[1] = pk2(kx[0].z*sc, kx[0].w*sc);
        pk.u[2] = pk2(kx[1].x*sc, kx[1].y*sc); pk.u[3] = pk2(kx[1].z*sc, kx[1].w*sc);
        *(short8*)&ks[buf][srow * 64 + ((cbk ^ ksw) << 3)] = pk.s8;      // b128
        union { unsigned int u[4]; short8 s8; } pv;
        pv.u[0] = pk2(vr[0], vr[1]); pv.u[1] = pk2(vr[2], vr[3]);
        pv.u[2] = pk2(vr[4], vr[5]); pv.u[3] = pk2(vr[6], vr[7]);
        *(short8*)&vt[buf][lane * 64 + vwin] = pv.s8;                    // b128
    };

    auto compute = [&](int buf) {
        const unsigned short* ksb = &ks[buf][0];
        const unsigned short* vsb = &vt[buf][0];
        #pragma unroll
        for (int g = 0; g < 2; g++) {
            // ---- S^T for 32 keys: A = K-frag (LDS b128), B = Q-frag (regs) ----
            floatx4 s[2][2];
            #pragma unroll
            for (int s2 = 0; s2 < 2; s2++) {
                int st = g * 2 + s2;
                short8 bk0 = *(const short8*)(ksb + (st * 16 + lam) * 64 + (((0 + quad) ^ sw) << 3));
                short8 bk1 = *(const short8*)(ksb + (st * 16 + lam) * 64 + (((4 + quad) ^ sw) << 3));
                #pragma unroll
                for (int t = 0; t < 2; t++) {
                    floatx4 acc = (floatx4){0.f, 0.f, 0.f, 0.f};
                    acc = __builtin_amdgcn_mfma_f32_16x16x32_bf16(bk0, aq[t][0], acc, 0, 0, 0);
                    acc = __builtin_amdgcn_mfma_f32_16x16x32_bf16(bk1, aq[t][1], acc, 0, 0, 0);
                    s[t][s2] = acc;
                }
            }
            // ---- exp2 + pack: S^T C-layout IS the PV A-fragment layout ----
            short8 pa[2];
            #pragma unroll
            for (int t = 0; t < 2; t++) {
                float e00 = __ocml_native_exp2_f32(s[t][0][0]);
                float e01 = __ocml_native_exp2_f32(s[t][0][1]);
                float e02 = __ocml_native_exp2_f32(s[t][0][2]);
                float e03 = __ocml_native_exp2_f32(s[t][0][3]);
                float e10 = __ocml_native_exp2_f32(s[t][1][0]);
                float e11 = __ocml_native_exp2_f32(s[t][1][1]);
                float e12 = __ocml_native_exp2_f32(s[t][1][2]);
                float e13 = __ocml_native_exp2_f32(s[t][1][3]);
                l[t] += ((e00 + e01) + (e02 + e03)) + ((e10 + e11) + (e12 + e13));
                union { unsigned int u[4]; short8 s8; } pk;
                pk.u[0] = pk2(e00, e01); pk.u[1] = pk2(e02, e03);
                pk.u[2] = pk2(e10, e11); pk.u[3] = pk2(e12, e13);
                pa[t] = pk.s8;
            }
            // ---- PV: B-frag = one b128 from vt (permuted V^T) ----
            #pragma unroll
            for (int dt = 0; dt < 4; dt++) {
                short8 bv = *(const short8*)(vsb + (dt * 16 + lam) * 64 + (((g * 4 + quad) ^ sw) << 3));
                #pragma unroll
                for (int t = 0; t < 2; t++)
                    oacc[t][dt] = __builtin_amdgcn_mfma_f32_16x16x32_bf16(pa[t], bv, oacc[t][dt], 0, 0, 0);
            }
        }
    };

    // ---- software-pipelined chunk loop: 1 barrier per chunk ----
    gload(0);
    stage(0);
    __syncthreads();
    for (int c = 0; c < 16; ++c) {
        int buf = c & 1;
        if (c < 15) gload(c + 1);      // regs prefetch overlaps compute
        compute(buf);
        if (c < 15) stage(buf ^ 1);    // waits on prefetch, writes other buffer
        __syncthreads();
    }

    // ---- epilogue: reduce l across quads, divide, store f32 ----
    const int b = head >> 4, hh = head & 15;
    #pragma unroll
    for (int t = 0; t < 2; t++) {
        float lr = l[t];
        lr += __shfl_xor(lr, 16);
        lr += __shfl_xor(lr, 32);
        float rl = 1.0f / lr;                    // lane lam holds 1/l for query t*16+lam
        float rq[4];
        #pragma unroll
        for (int r = 0; r < 4; r++) rq[r] = __shfl(rl, quad * 4 + r);
        float* ob = out + ((size_t)b * N_ + q0 + t * 16) * (H_ * D_) + hh * 64;
        #pragma unroll
        for (int dt = 0; dt < 4; dt++)
            #pragma unroll
            for (int r = 0; r < 4; r++)
                ob[(quad * 4 + r) * (H_ * D_) + dt * 16 + lam] = oacc[t][dt][r] * rq[r];
    }
}

extern "C" void kernel_launch(void* const* d_in, const int* in_sizes, int n_in,
                              void* d_out, int out_size, void* d_ws, size_t ws_size,
                              hipStream_t stream) {
    const float* q = (const float*)d_in[0];
    const float* k = (const float*)d_in[1];
    const float* v = (const float*)d_in[2];
    float* out = (float*)d_out;
    (void)d_ws; (void)ws_size;
    hipLaunchKernelGGL(attn_fused, dim3(NH_ * 4), dim3(512), 0, stream, q, k, v, out);
}